// Round 11
// baseline (293.873 us; speedup 1.0000x reference)
//
#include <hip/hip_runtime.h>
#include <hip/hip_bf16.h>
#include <stdint.h>

typedef __attribute__((ext_vector_type(4))) int i32x4;
typedef __attribute__((ext_vector_type(4))) float f32x4;

#define THRESH 0.3f
#define Mdim 8192
#define Kdim 2048
#define Ndim 8192
#define NT 16   // K-tiles of 128 (i8)
#define NIT 8   // 2 K-tiles per iteration

// ---- Pass 1a: x fp32 -> i8 with per-row scale ----
__global__ void xq_kernel(const float* __restrict__ x,
                          signed char* __restrict__ xq,
                          float* __restrict__ scales) {
  int row = blockIdx.x;
  int tid = threadIdx.x;  // 256
  const float* xr = x + (long)row * Kdim;
  float4 a = ((const float4*)xr)[tid * 2];
  float4 b = ((const float4*)xr)[tid * 2 + 1];
  float m = fmaxf(fmaxf(fmaxf(fabsf(a.x), fabsf(a.y)),
                        fmaxf(fabsf(a.z), fabsf(a.w))),
                  fmaxf(fmaxf(fabsf(b.x), fabsf(b.y)),
                        fmaxf(fabsf(b.z), fabsf(b.w))));
  #pragma unroll
  for (int d = 1; d < 64; d <<= 1) m = fmaxf(m, __shfl_xor(m, d, 64));
  __shared__ float red[4];
  if ((tid & 63) == 0) red[tid >> 6] = m;
  __syncthreads();
  m = fmaxf(fmaxf(red[0], red[1]), fmaxf(red[2], red[3]));
  m = fmaxf(m, 1e-20f);
  float inv = 127.0f / m;
  int q0 = (int)rintf(a.x * inv), q1 = (int)rintf(a.y * inv);
  int q2 = (int)rintf(a.z * inv), q3 = (int)rintf(a.w * inv);
  int q4 = (int)rintf(b.x * inv), q5 = (int)rintf(b.y * inv);
  int q6 = (int)rintf(b.z * inv), q7 = (int)rintf(b.w * inv);
  int lo = (q0 & 0xFF) | ((q1 & 0xFF) << 8) | ((q2 & 0xFF) << 16) |
           ((q3 & 0xFF) << 24);
  int hi = (q4 & 0xFF) | ((q5 & 0xFF) << 8) | ((q6 & 0xFF) << 16) |
           ((q7 & 0xFF) << 24);
  ((int2*)(xq + (long)row * Kdim))[tid] = make_int2(lo, hi);
  if (tid == 0) scales[row] = m / 127.0f;
}

// ---- Pass 1b: w [K][N] fp32 -> ternary i8 transposed [N][K] ----
__global__ void tern_tr_kernel(const float* __restrict__ w,
                               signed char* __restrict__ bt) {
  __shared__ signed char tile[32][33];
  int n0 = blockIdx.x * 32, k0 = blockIdx.y * 32;
  int tx = threadIdx.x, ty = threadIdx.y;  // (32, 8)
  #pragma unroll
  for (int j = 0; j < 4; ++j) {
    int k = k0 + ty + j * 8;
    float v = w[(long)k * Ndim + n0 + tx];
    signed char t = (fabsf(v) > THRESH) ? (v > 0.f ? 1 : -1) : 0;
    tile[ty + j * 8][tx] = t;
  }
  __syncthreads();
  int t = ty * 32 + tx;
  int nl = t >> 3, kq = t & 7;
  int b0 = tile[kq * 4 + 0][nl] & 0xFF;
  int b1 = tile[kq * 4 + 1][nl] & 0xFF;
  int b2 = tile[kq * 4 + 2][nl] & 0xFF;
  int b3 = tile[kq * 4 + 3][nl] & 0xFF;
  int pk = b0 | (b1 << 8) | (b2 << 16) | (b3 << 24);
  *(int*)(bt + (long)(n0 + nl) * Kdim + k0 + kq * 4) = pk;
}

// ---- Pass 2: 256x256 i8 MFMA GEMM, C = scale_m * (Aq * Bt^T) ----
// R11: R9's verified skeleton (8 barriers/tile, explicit per-phase lgkm(0),
// counted vmcnt gate, setprio, XOR-swizzled A staging). CHANGE: B no longer
// goes through LDS. bf[8] loads issue directly global->VGPR at tile top
// (B panel is L1/L2-hot: 32KB/tile shared by 8 waves + XCD-chunked blocks).
// Removes 64 of 192 ds_read_b128 per CU-tile (~770cy of the serialized LDS
// term in R9's 5750cy/tile model), halves staging loads + gate depth.
// LDS = A triple-buffer only = 96 KiB.
__global__ void __launch_bounds__(512, 1) gemm8_kernel(
    const signed char* __restrict__ A,   // [8192][2048] i8 (M-major)
    const signed char* __restrict__ Bt,  // [8192][2048] i8 (N-major)
    const float* __restrict__ scales,    // [8192] per-M-row dequant scale
    float* __restrict__ C) {             // [8192][8192] fp32
  // layout: Abuf[j] at j*32768 (j=0..2)
  __shared__ __align__(128) char lds[98304];

  int bid = blockIdx.x;
  // 2D XCD-chunked swizzle (bijective over 32x32 tiles), R4-verified.
  int x = bid & 7;
  int o = bid >> 3;
  int c = o >> 5;
  int w = o & 31;
  int tm = x * 4 + (w >> 3);
  int tn = c * 8 + (w & 7);
  long arow0 = (long)tm * 256;
  long bcol0 = (long)tn * 256;

  int tid = threadIdx.x;
  int lane = tid & 63, wid = tid >> 6;
  int wr = wid >> 2, wc = wid & 3;  // 2M x 4N waves; per-wave C = 128x64
  int lr = lane & 15, lk = lane >> 4;

  // precomputed per-lane LDS read offsets for A (R7-verified algebra)
  int x7 = lr & 7;
  int voA[2];
  #pragma unroll
  for (int ks = 0; ks < 2; ++ks)
    voA[ks] = (wr * 128 + lr) * 128 + ((((ks * 4 + lk) ^ x7)) << 4);

  // precomputed per-thread A staging offsets
  int go[2][2];  // [h][cc]
  #pragma unroll
  for (int h = 0; h < 2; ++h)
    #pragma unroll
    for (int cc = 0; cc < 2; ++cc) {
      int s = cc * 512 + tid;
      int r = h * 128 + (s >> 3);
      int co = (s & 7) ^ (r & 7);
      go[h][cc] = r * Kdim + co * 16;
    }
  const char* baseA = (const char*)A + arow0 * (long)Kdim;
  // per-lane B base: row = bcol0 + wc*64 + lr (+n*16), k-byte = lk*16 (+ks*64)
  const char* baseBlane =
      (const char*)Bt + (bcol0 + wc * 64 + lr) * (long)Kdim + lk * 16;
  int ldst[2] = {(0 * 512 + wid * 64) * 16, (1 * 512 + wid * 64) * 16};

  auto stage = [&](int u, int h) {
    if (u >= NT) return;
    int base = (u % 3) * 32768 + h * 16384;
    int ub = u * 128;
    #pragma unroll
    for (int cc = 0; cc < 2; ++cc) {
      const char* g = baseA + (long)(go[h][cc] + ub);
      __builtin_amdgcn_global_load_lds(
          (const __attribute__((address_space(1))) void*)g,
          (__attribute__((address_space(3))) void*)(lds + base + ldst[cc]),
          16, 0, 0);
    }
  };

  i32x4 acc[8][4] = {};
  i32x4 bf[4][2];

  // prologue: A tiles 0,1 staged (8 loads); wait for tile 0's 4.
  stage(0, 0); stage(0, 1); stage(1, 0); stage(1, 1);
  asm volatile("s_waitcnt vmcnt(4)" ::: "memory");
  __builtin_amdgcn_s_barrier();

  for (int it = 0; it < NIT; ++it) {
    int t = 2 * it;
    #pragma unroll
    for (int half = 0; half < 2; ++half) {
      int cur = t + half;
      const char* pA0 = lds + (cur % 3) * 32768 + voA[0];
      const char* pA1 = lds + (cur % 3) * 32768 + voA[1];
      int u = cur + 2;  // A stage target tile

      // tile top: B fragments straight from global (L1/L2-served; linear
      // layout, no swizzle). Compiler inserts the counted vmcnt wait
      // before q0's first MFMA using bf (drains A(u+1) stages too).
      const char* pB = baseBlane + (long)cur * 128;
      #pragma unroll
      for (int n = 0; n < 4; ++n) {
        bf[n][0] = *(const i32x4*)(pB + n * 16 * Kdim);
        bf[n][1] = *(const i32x4*)(pB + n * 16 * Kdim + 64);
      }

      #pragma unroll
      for (int q = 0; q < 4; ++q) {
        // ds-load A register subtile for this phase (immediates fold)
        i32x4 af[2][2];
        #pragma unroll
        for (int m = 0; m < 2; ++m) {
          af[m][0] = *(const i32x4*)(pA0 + q * 4096 + m * 2048);
          af[m][1] = *(const i32x4*)(pA1 + q * 4096 + m * 2048);
        }
        // A staging slots: q0 -> half 0, q1 -> half 1 of tile cur+2
        if (q == 0) stage(u, 0);
        else if (q == 1) stage(u, 1);

        __builtin_amdgcn_s_barrier();
        asm volatile("s_waitcnt lgkmcnt(0)" ::: "memory");
        __builtin_amdgcn_s_setprio(1);
        #pragma unroll
        for (int ks = 0; ks < 2; ++ks)
          #pragma unroll
          for (int m = 0; m < 2; ++m)
            #pragma unroll
            for (int n = 0; n < 4; ++n)
              acc[q * 2 + m][n] = __builtin_amdgcn_mfma_i32_16x16x64_i8(
                  af[m][ks], bf[n][ks], acc[q * 2 + m][n], 0, 0, 0);
        __builtin_amdgcn_s_setprio(0);
        if (q == 3) {
          // gate: exempt exactly this tile's 4 in-flight A stages (ensures
          // A(u+1) landed); drain fully when stages were skipped (tail).
          if (u < NT) asm volatile("s_waitcnt vmcnt(4)" ::: "memory");
          else        asm volatile("s_waitcnt vmcnt(0)" ::: "memory");
        }
        __builtin_amdgcn_s_barrier();
      }
    }
  }

  // epilogue: D row = lk*4 + reg, col = lr; out = acc * scale[row]
  #pragma unroll
  for (int m = 0; m < 8; ++m) {
    long row0 = arow0 + wr * 128 + m * 16 + lk * 4;
    f32x4 sc = *(const f32x4*)(scales + row0);
    #pragma unroll
    for (int n = 0; n < 4; ++n) {
      long col = bcol0 + wc * 64 + n * 16 + lr;
      #pragma unroll
      for (int r = 0; r < 4; ++r)
        C[(row0 + r) * Ndim + col] = (float)acc[m][n][r] * sc[r];
    }
  }
}

// ---- fallback if d_ws is too small: simple tiled fp32 GEMM ----
__global__ void fallback_gemm(const float* __restrict__ x,
                              const float* __restrict__ w,
                              float* __restrict__ C) {
  __shared__ float As[16][17];
  __shared__ float Bs[16][17];
  int tx = threadIdx.x, ty = threadIdx.y;
  long row = (long)blockIdx.y * 16 + ty;
  long col = (long)blockIdx.x * 16 + tx;
  float s = 0.f;
  for (int k0 = 0; k0 < Kdim; k0 += 16) {
    As[ty][tx] = x[row * Kdim + k0 + tx];
    float v = w[(long)(k0 + ty) * Ndim + col];
    Bs[ty][tx] = (fabsf(v) > THRESH) ? (v > 0.f ? 1.f : -1.f) : 0.f;
    __syncthreads();
    #pragma unroll
    for (int k = 0; k < 16; ++k) s += As[ty][k] * Bs[k][tx];
    __syncthreads();
  }
  C[row * Ndim + col] = s;
}

extern "C" void kernel_launch(void* const* d_in, const int* in_sizes, int n_in,
                              void* d_out, int out_size, void* d_ws, size_t ws_size,
                              hipStream_t stream) {
  const float* x = (const float*)d_in[0];
  const float* w = (const float*)d_in[1];
  float* out = (float*)d_out;

  size_t abytes = (size_t)Mdim * Kdim;      // 16 MB i8
  size_t bbytes = (size_t)Ndim * Kdim;      // 16 MB i8
  size_t sbytes = (size_t)Mdim * 4;         // 32 KB scales

  if (ws_size >= abytes + bbytes + sbytes) {
    signed char* xq = (signed char*)d_ws;
    signed char* bt = (signed char*)d_ws + abytes;
    float* scales = (float*)((char*)d_ws + abytes + bbytes);
    xq_kernel<<<Mdim, 256, 0, stream>>>(x, xq, scales);
    tern_tr_kernel<<<dim3(Ndim / 32, Kdim / 32), dim3(32, 8), 0, stream>>>(w, bt);
    gemm8_kernel<<<1024, 512, 0, stream>>>(xq, bt, scales, out);
  } else {
    fallback_gemm<<<dim3(Ndim / 16, Mdim / 16), dim3(16, 16), 0, stream>>>(x, w, out);
  }
}

// Round 12
// 190.606 us; speedup vs baseline: 1.5418x; 1.5418x over previous
//
#include <hip/hip_runtime.h>
#include <hip/hip_bf16.h>
#include <stdint.h>

typedef __attribute__((ext_vector_type(4))) int i32x4;
typedef __attribute__((ext_vector_type(4))) float f32x4;

#define THRESH 0.3f
#define Mdim 8192
#define Kdim 2048
#define Ndim 8192
#define NT 32   // K-tiles of 64 (i8)

// ---- Pass 1a: x fp32 -> i8 with per-row scale ----
__global__ void xq_kernel(const float* __restrict__ x,
                          signed char* __restrict__ xq,
                          float* __restrict__ scales) {
  int row = blockIdx.x;
  int tid = threadIdx.x;  // 256
  const float* xr = x + (long)row * Kdim;
  float4 a = ((const float4*)xr)[tid * 2];
  float4 b = ((const float4*)xr)[tid * 2 + 1];
  float m = fmaxf(fmaxf(fmaxf(fabsf(a.x), fabsf(a.y)),
                        fmaxf(fabsf(a.z), fabsf(a.w))),
                  fmaxf(fmaxf(fabsf(b.x), fabsf(b.y)),
                        fmaxf(fabsf(b.z), fabsf(b.w))));
  #pragma unroll
  for (int d = 1; d < 64; d <<= 1) m = fmaxf(m, __shfl_xor(m, d, 64));
  __shared__ float red[4];
  if ((tid & 63) == 0) red[tid >> 6] = m;
  __syncthreads();
  m = fmaxf(fmaxf(red[0], red[1]), fmaxf(red[2], red[3]));
  m = fmaxf(m, 1e-20f);
  float inv = 127.0f / m;
  int q0 = (int)rintf(a.x * inv), q1 = (int)rintf(a.y * inv);
  int q2 = (int)rintf(a.z * inv), q3 = (int)rintf(a.w * inv);
  int q4 = (int)rintf(b.x * inv), q5 = (int)rintf(b.y * inv);
  int q6 = (int)rintf(b.z * inv), q7 = (int)rintf(b.w * inv);
  int lo = (q0 & 0xFF) | ((q1 & 0xFF) << 8) | ((q2 & 0xFF) << 16) |
           ((q3 & 0xFF) << 24);
  int hi = (q4 & 0xFF) | ((q5 & 0xFF) << 8) | ((q6 & 0xFF) << 16) |
           ((q7 & 0xFF) << 24);
  ((int2*)(xq + (long)row * Kdim))[tid] = make_int2(lo, hi);
  if (tid == 0) scales[row] = m / 127.0f;
}

// ---- Pass 1b: w [K][N] fp32 -> ternary i8 transposed [N][K] ----
__global__ void tern_tr_kernel(const float* __restrict__ w,
                               signed char* __restrict__ bt) {
  __shared__ signed char tile[32][33];
  int n0 = blockIdx.x * 32, k0 = blockIdx.y * 32;
  int tx = threadIdx.x, ty = threadIdx.y;  // (32, 8)
  #pragma unroll
  for (int j = 0; j < 4; ++j) {
    int k = k0 + ty + j * 8;
    float v = w[(long)k * Ndim + n0 + tx];
    signed char t = (fabsf(v) > THRESH) ? (v > 0.f ? 1 : -1) : 0;
    tile[ty + j * 8][tx] = t;
  }
  __syncthreads();
  int t = ty * 32 + tx;
  int nl = t >> 3, kq = t & 7;
  int b0 = tile[kq * 4 + 0][nl] & 0xFF;
  int b1 = tile[kq * 4 + 1][nl] & 0xFF;
  int b2 = tile[kq * 4 + 2][nl] & 0xFF;
  int b3 = tile[kq * 4 + 3][nl] & 0xFF;
  int pk = b0 | (b1 << 8) | (b2 << 16) | (b3 << 24);
  *(int*)(bt + (long)(n0 + nl) * Kdim + k0 + kq * 4) = pk;
}

// ---- Pass 2: 256x128 i8 MFMA GEMM, C = scale_m * (Aq * Bt^T) ----
// R12: occupancy attack. R9's 5750cy/tile = MFMA 2613 + LDS 2300 + sync,
// serialized because 1 block/CU leaves no work to fill each phase's stalls.
// This kernel: BM=256 BN=128 BK=64, 8 waves of 64x64 (acc=64 VGPR) ->
// <=128 VGPR/wave -> 16 waves/CU = 2 BLOCKS/CU; blocks have independent
// barriers so one block's MFMA overlaps the other's LDS/staging (m114).
// BK=64 => 64B rows => every wave fragment read is a contiguous 1KB =>
// conflict-free with NO swizzle; staging is plain linear global_load_lds.
// Schedule keeps R9's verified invariants: depth-2 prefetch, triple
// buffers, counted vmcnt(3) gate (exempt this tile's 3 loads), vmcnt(0)
// tail, one barrier + one lgkmcnt(0) per tile.
__global__ void __launch_bounds__(512, 4) gemm8_kernel(
    const signed char* __restrict__ A,   // [8192][2048] i8 (M-major)
    const signed char* __restrict__ Bt,  // [8192][2048] i8 (N-major)
    const float* __restrict__ scales,    // [8192] per-M-row dequant scale
    float* __restrict__ C) {             // [8192][8192] fp32
  // layout: Abuf[j] at j*16384 (j=0..2, 256x64B); Bbuf[j] at 49152+j*8192
  __shared__ __align__(128) char lds[73728];

  int bid = blockIdx.x;
  // 2D XCD-chunked swizzle, bijective over 32(tm) x 64(tn):
  // XCD x owns tm-band [4x,4x+4); chunks of 4(tm) x 16(tn) = 64 blocks
  // = the concurrent set at 2 blocks/CU; same tn-chunk across XCDs -> B
  // panels served by L3 once.
  int x = bid & 7;
  int o = bid >> 3;        // 0..255
  int c = o >> 6;          // tn-chunk 0..3
  int w = o & 63;
  int tm = x * 4 + (w >> 4);   // 0..31
  int tn = c * 16 + (w & 15);  // 0..63
  long arow0 = (long)tm * 256;
  long bcol0 = (long)tn * 128;

  int tid = threadIdx.x;
  int lane = tid & 63, wid = tid >> 6;
  int wr = wid >> 1, wc = wid & 1;  // 4M x 2N waves; per-wave C = 64x64
  int lr = lane & 15, lk = lane >> 4;

  // per-lane LDS fragment offsets: row*64 + lk*16 (contiguous 1KB/wave/frag)
  int voA = (wr * 64 + lr) * 64 + lk * 16;
  int voB = (wc * 64 + lr) * 64 + lk * 16;

  // per-thread staging source offsets (linear; slot = tid)
  int r = tid >> 2, ch = tid & 3;
  int goA0 = r * Kdim + ch * 16;              // h=0 rows 0..127
  int goA1 = (128 + r) * Kdim + ch * 16;      // h=1 rows 128..255
  int goB = r * Kdim + ch * 16;               // rows 0..127
  const char* baseA = (const char*)A + arow0 * (long)Kdim;
  const char* baseB = (const char*)Bt + bcol0 * (long)Kdim;
  int wdst = wid * 1024;  // wave-uniform LDS dest base (HW adds lane*16)

  auto stageA = [&](int u, int h) {
    if (u >= NT) return;
    const char* g = baseA + (long)((h ? goA1 : goA0) + u * 64);
    __builtin_amdgcn_global_load_lds(
        (const __attribute__((address_space(1))) void*)g,
        (__attribute__((address_space(3))) void*)(
            lds + (u % 3) * 16384 + h * 8192 + wdst),
        16, 0, 0);
  };
  auto stageB = [&](int u) {
    if (u >= NT) return;
    const char* g = baseB + (long)(goB + u * 64);
    __builtin_amdgcn_global_load_lds(
        (const __attribute__((address_space(1))) void*)g,
        (__attribute__((address_space(3))) void*)(
            lds + 49152 + (u % 3) * 8192 + wdst),
        16, 0, 0);
  };

  i32x4 acc[4][4] = {};

  // prologue: tiles 0,1 staged (3 loads each); wait tile 0's 3, tile 1 in
  // flight (vmcnt(3)).
  stageA(0, 0); stageA(0, 1); stageB(0);
  stageA(1, 0); stageA(1, 1); stageB(1);
  asm volatile("s_waitcnt vmcnt(3)" ::: "memory");
  __builtin_amdgcn_s_barrier();

  for (int u = 0; u < NT; ++u) {
    const char* pA = lds + (u % 3) * 16384 + voA;
    const char* pB = lds + 49152 + (u % 3) * 8192 + voB;

    // fragment reads (ds_read_b128 x8, contiguous per wave, imm offsets)
    i32x4 af[4], bf[4];
    #pragma unroll
    for (int m = 0; m < 4; ++m) af[m] = *(const i32x4*)(pA + m * 1024);
    #pragma unroll
    for (int n = 0; n < 4; ++n) bf[n] = *(const i32x4*)(pB + n * 1024);

    // depth-2 prefetch of tile u+2 (buf (u+2)%3 holds u-1: all reads of it
    // completed before the barrier that ended tile u-1)
    stageA(u + 2, 0); stageA(u + 2, 1); stageB(u + 2);

    asm volatile("s_waitcnt lgkmcnt(0)" ::: "memory");
    __builtin_amdgcn_s_setprio(1);
    #pragma unroll
    for (int m = 0; m < 4; ++m)
      #pragma unroll
      for (int n = 0; n < 4; ++n)
        acc[m][n] = __builtin_amdgcn_mfma_i32_16x16x64_i8(
            af[m], bf[n], acc[m][n], 0, 0, 0);
    __builtin_amdgcn_s_setprio(0);

    // gate: exempt this tile's 3 in-flight stages; everything older
    // (tile u+1's loads) must have landed. Tail: drain fully.
    if (u + 2 < NT) asm volatile("s_waitcnt vmcnt(3)" ::: "memory");
    else            asm volatile("s_waitcnt vmcnt(0)" ::: "memory");
    __builtin_amdgcn_s_barrier();
  }

  // epilogue: D row = lk*4 + reg, col = lr; out = acc * scale[row]
  #pragma unroll
  for (int m = 0; m < 4; ++m) {
    long row0 = arow0 + wr * 64 + m * 16 + lk * 4;
    f32x4 sc = *(const f32x4*)(scales + row0);
    #pragma unroll
    for (int n = 0; n < 4; ++n) {
      long col = bcol0 + wc * 64 + n * 16 + lr;
      #pragma unroll
      for (int rr = 0; rr < 4; ++rr)
        C[(row0 + rr) * Ndim + col] = (float)acc[m][n][rr] * sc[rr];
    }
  }
}

// ---- fallback if d_ws is too small: simple tiled fp32 GEMM ----
__global__ void fallback_gemm(const float* __restrict__ x,
                              const float* __restrict__ w,
                              float* __restrict__ C) {
  __shared__ float As[16][17];
  __shared__ float Bs[16][17];
  int tx = threadIdx.x, ty = threadIdx.y;
  long row = (long)blockIdx.y * 16 + ty;
  long col = (long)blockIdx.x * 16 + tx;
  float s = 0.f;
  for (int k0 = 0; k0 < Kdim; k0 += 16) {
    As[ty][tx] = x[row * Kdim + k0 + tx];
    float v = w[(long)(k0 + ty) * Ndim + col];
    Bs[ty][tx] = (fabsf(v) > THRESH) ? (v > 0.f ? 1.f : -1.f) : 0.f;
    __syncthreads();
    #pragma unroll
    for (int k = 0; k < 16; ++k) s += As[ty][k] * Bs[k][tx];
    __syncthreads();
  }
  C[row * Ndim + col] = s;
}

extern "C" void kernel_launch(void* const* d_in, const int* in_sizes, int n_in,
                              void* d_out, int out_size, void* d_ws, size_t ws_size,
                              hipStream_t stream) {
  const float* x = (const float*)d_in[0];
  const float* w = (const float*)d_in[1];
  float* out = (float*)d_out;

  size_t abytes = (size_t)Mdim * Kdim;      // 16 MB i8
  size_t bbytes = (size_t)Ndim * Kdim;      // 16 MB i8
  size_t sbytes = (size_t)Mdim * 4;         // 32 KB scales

  if (ws_size >= abytes + bbytes + sbytes) {
    signed char* xq = (signed char*)d_ws;
    signed char* bt = (signed char*)d_ws + abytes;
    float* scales = (float*)((char*)d_ws + abytes + bbytes);
    xq_kernel<<<Mdim, 256, 0, stream>>>(x, xq, scales);
    tern_tr_kernel<<<dim3(Ndim / 32, Kdim / 32), dim3(32, 8), 0, stream>>>(w, bt);
    gemm8_kernel<<<2048, 512, 0, stream>>>(xq, bt, scales, out);
  } else {
    fallback_gemm<<<dim3(Ndim / 16, Mdim / 16), dim3(16, 16), 0, stream>>>(x, w, out);
  }
}

// Round 13
// 187.091 us; speedup vs baseline: 1.5707x; 1.0188x over previous
//
#include <hip/hip_runtime.h>
#include <hip/hip_bf16.h>
#include <stdint.h>

typedef __attribute__((ext_vector_type(4))) int i32x4;
typedef __attribute__((ext_vector_type(4))) float f32x4;

#define THRESH 0.3f
#define Mdim 8192
#define Kdim 2048
#define Ndim 8192
#define NT 16   // K-tiles of 128 (i8)
#define NIT 8   // 2 K-tiles per iteration

// ---- Pass 1a: x fp32 -> i8 with per-row scale ----
__global__ void xq_kernel(const float* __restrict__ x,
                          signed char* __restrict__ xq,
                          float* __restrict__ scales) {
  int row = blockIdx.x;
  int tid = threadIdx.x;  // 256
  const float* xr = x + (long)row * Kdim;
  float4 a = ((const float4*)xr)[tid * 2];
  float4 b = ((const float4*)xr)[tid * 2 + 1];
  float m = fmaxf(fmaxf(fmaxf(fabsf(a.x), fabsf(a.y)),
                        fmaxf(fabsf(a.z), fabsf(a.w))),
                  fmaxf(fmaxf(fabsf(b.x), fabsf(b.y)),
                        fmaxf(fabsf(b.z), fabsf(b.w))));
  #pragma unroll
  for (int d = 1; d < 64; d <<= 1) m = fmaxf(m, __shfl_xor(m, d, 64));
  __shared__ float red[4];
  if ((tid & 63) == 0) red[tid >> 6] = m;
  __syncthreads();
  m = fmaxf(fmaxf(red[0], red[1]), fmaxf(red[2], red[3]));
  m = fmaxf(m, 1e-20f);
  float inv = 127.0f / m;
  int q0 = (int)rintf(a.x * inv), q1 = (int)rintf(a.y * inv);
  int q2 = (int)rintf(a.z * inv), q3 = (int)rintf(a.w * inv);
  int q4 = (int)rintf(b.x * inv), q5 = (int)rintf(b.y * inv);
  int q6 = (int)rintf(b.z * inv), q7 = (int)rintf(b.w * inv);
  int lo = (q0 & 0xFF) | ((q1 & 0xFF) << 8) | ((q2 & 0xFF) << 16) |
           ((q3 & 0xFF) << 24);
  int hi = (q4 & 0xFF) | ((q5 & 0xFF) << 8) | ((q6 & 0xFF) << 16) |
           ((q7 & 0xFF) << 24);
  ((int2*)(xq + (long)row * Kdim))[tid] = make_int2(lo, hi);
  if (tid == 0) scales[row] = m / 127.0f;
}

// ---- Pass 1b: w [K][N] fp32 -> ternary i8 transposed [N][K] ----
__global__ void tern_tr_kernel(const float* __restrict__ w,
                               signed char* __restrict__ bt) {
  __shared__ signed char tile[32][33];
  int n0 = blockIdx.x * 32, k0 = blockIdx.y * 32;
  int tx = threadIdx.x, ty = threadIdx.y;  // (32, 8)
  #pragma unroll
  for (int j = 0; j < 4; ++j) {
    int k = k0 + ty + j * 8;
    float v = w[(long)k * Ndim + n0 + tx];
    signed char t = (fabsf(v) > THRESH) ? (v > 0.f ? 1 : -1) : 0;
    tile[ty + j * 8][tx] = t;
  }
  __syncthreads();
  int t = ty * 32 + tx;
  int nl = t >> 3, kq = t & 7;
  int b0 = tile[kq * 4 + 0][nl] & 0xFF;
  int b1 = tile[kq * 4 + 1][nl] & 0xFF;
  int b2 = tile[kq * 4 + 2][nl] & 0xFF;
  int b3 = tile[kq * 4 + 3][nl] & 0xFF;
  int pk = b0 | (b1 << 8) | (b2 << 16) | (b3 << 24);
  *(int*)(bt + (long)(n0 + nl) * Kdim + k0 + kq * 4) = pk;
}

// ---- Pass 2: 256x256 i8 MFMA GEMM, C = scale_m * (Aq * Bt^T) ----
// R13: convoy-break. R9's 5750cy/tile == MFMA(2616) + DS(2304) + sync(800):
// the per-phase barriers globally separate the DS segment from the MFMA
// segment, so the two pipes never overlap. This kernel keeps R9's geometry,
// buffers, staging and vmcnt gates, but removes intra-tile phase barriers
// and gives each wave a ROTATED phase order q=(s+wid)&3 (static acc slot s;
// rotation only in addresses) so at any instant some waves feed the DS pipe
// while others feed the MFMA pipe (m114 overlap, forced structurally --
// R6's no-rotation free-run convoyed and failed). One mid-tile barrier
// guards the B(cur+2)->B(cur&1) buffer overwrite (all bf reads complete by
// then); A(cur+2) stages at tile top (its buffer was fully read last tile).
__global__ void __launch_bounds__(512, 1) gemm8_kernel(
    const signed char* __restrict__ A,   // [8192][2048] i8 (M-major)
    const signed char* __restrict__ Bt,  // [8192][2048] i8 (N-major)
    const float* __restrict__ scales,    // [8192] per-M-row dequant scale
    float* __restrict__ C) {             // [8192][8192] fp32
  // layout: Abuf[j] at j*32768 (j=0..2); Bbuf[j] at 98304 + j*32768 (j=0..1)
  __shared__ __align__(128) char lds[163840];

  int bid = blockIdx.x;
  // 2D XCD-chunked swizzle (bijective over 32x32 tiles), R4-verified.
  int x = bid & 7;
  int o = bid >> 3;
  int c = o >> 5;
  int w = o & 31;
  int tm = x * 4 + (w >> 3);
  int tn = c * 8 + (w & 7);
  long arow0 = (long)tm * 256;
  long bcol0 = (long)tn * 256;

  int tid = threadIdx.x;
  int lane = tid & 63, wid = tid >> 6;
  int wr = wid >> 2, wc = wid & 3;  // 2M x 4N waves; per-wave C = 128x64
  int lr = lane & 15, lk = lane >> 4;

  // precomputed per-lane LDS read offsets (R7-verified algebra)
  int x7 = lr & 7;
  int voA[2], voB[2];
  #pragma unroll
  for (int ks = 0; ks < 2; ++ks) {
    int xo = ((ks * 4 + lk) ^ x7) << 4;
    voA[ks] = (wr * 128 + lr) * 128 + xo;
    voB[ks] = (wc * 64 + lr) * 128 + xo;
  }

  // precomputed per-thread staging offsets
  int go[2][2];  // [h][cc]
  #pragma unroll
  for (int h = 0; h < 2; ++h)
    #pragma unroll
    for (int cc = 0; cc < 2; ++cc) {
      int s = cc * 512 + tid;
      int r = h * 128 + (s >> 3);
      int co = (s & 7) ^ (r & 7);
      go[h][cc] = r * Kdim + co * 16;
    }
  const char* baseA = (const char*)A + arow0 * (long)Kdim;
  const char* baseB = (const char*)Bt + bcol0 * (long)Kdim;
  int ldst[2] = {(0 * 512 + wid * 64) * 16, (1 * 512 + wid * 64) * 16};

  auto stage = [&](int u, int which, int h) {
    if (u >= NT) return;
    const char* gb = which ? baseB : baseA;
    int base = (which ? (98304 + (u & 1) * 32768) : ((u % 3) * 32768)) +
               h * 16384;
    int ub = u * 128;
    #pragma unroll
    for (int cc = 0; cc < 2; ++cc) {
      const char* g = gb + (long)(go[h][cc] + ub);
      __builtin_amdgcn_global_load_lds(
          (const __attribute__((address_space(1))) void*)g,
          (__attribute__((address_space(3))) void*)(lds + base + ldst[cc]),
          16, 0, 0);
    }
  };

  i32x4 acc[8][4] = {};
  i32x4 bf[4][2];
  int rot = wid & 3;  // wave's phase rotation

  // prologue: tiles 0 and 1 fully staged (16 loads); wait for tile 0's 8.
  stage(0, 0, 0); stage(0, 0, 1); stage(0, 1, 0); stage(0, 1, 1);
  stage(1, 0, 0); stage(1, 0, 1); stage(1, 1, 0); stage(1, 1, 1);
  asm volatile("s_waitcnt vmcnt(8)" ::: "memory");
  __builtin_amdgcn_s_barrier();

  for (int it = 0; it < NIT; ++it) {
    int t = 2 * it;
    #pragma unroll
    for (int half = 0; half < 2; ++half) {
      int cur = t + half;
      const char* pA0 = lds + (cur % 3) * 32768 + voA[0];
      const char* pA1 = lds + (cur % 3) * 32768 + voA[1];
      const char* pB0 = lds + 98304 + (cur & 1) * 32768 + voB[0];
      const char* pB1 = lds + 98304 + (cur & 1) * 32768 + voB[1];
      int u = cur + 2;  // stage target tile

      // A(cur+2) stages at tile top: target buf (cur+2)%3 == (cur-1)%3,
      // whose reads all completed before the barrier that ended tile cur-1.
      stage(u, 0, 0); stage(u, 0, 1);

      // B fragments for the whole tile (compiler inserts counted lgkm
      // waits before first use).
      #pragma unroll
      for (int n = 0; n < 4; ++n) {
        bf[n][0] = *(const i32x4*)(pB0 + n * 2048);
        bf[n][1] = *(const i32x4*)(pB1 + n * 2048);
      }

      // free-run phases, rotated per wave: static acc slot s, row-quadrant
      // q = (s + rot) & 3 appears only in addresses/epilogue (no dynamic
      // acc indexing -> no scratch).
      #pragma unroll
      for (int s = 0; s < 4; ++s) {
        int q = (s + rot) & 3;
        i32x4 af[2][2];
        #pragma unroll
        for (int m = 0; m < 2; ++m) {
          af[m][0] = *(const i32x4*)(pA0 + q * 4096 + m * 2048);
          af[m][1] = *(const i32x4*)(pA1 + q * 4096 + m * 2048);
        }
        __builtin_amdgcn_s_setprio(1);
        #pragma unroll
        for (int ks = 0; ks < 2; ++ks)
          #pragma unroll
          for (int m = 0; m < 2; ++m)
            #pragma unroll
            for (int n = 0; n < 4; ++n)
              acc[s * 2 + m][n] = __builtin_amdgcn_mfma_i32_16x16x64_i8(
                  af[m][ks], bf[n][ks], acc[s * 2 + m][n], 0, 0, 0);
        __builtin_amdgcn_s_setprio(0);

        if (s == 1) {
          // mid-tile barrier: every wave has completed its bf reads (they
          // complete before that wave's first MFMA in s=0). B(cur+2) may
          // now overwrite B buffer (cur+2)&1 == cur&1.
          __builtin_amdgcn_s_barrier();
          stage(u, 1, 0); stage(u, 1, 1);
        }
      }

      // gate: exempt exactly this tile's 8 in-flight stages (4 A top +
      // 4 B mid); everything older (tile cur+1's loads) must have landed.
      // Tail (stages skipped): drain fully (round-2 lesson).
      if (u < NT) asm volatile("s_waitcnt vmcnt(8)" ::: "memory");
      else        asm volatile("s_waitcnt vmcnt(0)" ::: "memory");
      __builtin_amdgcn_s_barrier();
    }
  }

  // epilogue: D row = lk*4 + reg, col = lr; slot s holds row-quadrant
  // (s + rot) & 3; out = acc * scale[row]
  #pragma unroll
  for (int s = 0; s < 4; ++s) {
    int q = (s + rot) & 3;
    #pragma unroll
    for (int m = 0; m < 2; ++m) {
      long row0 = arow0 + wr * 128 + (q * 2 + m) * 16 + lk * 4;
      f32x4 sc = *(const f32x4*)(scales + row0);
      #pragma unroll
      for (int n = 0; n < 4; ++n) {
        long col = bcol0 + wc * 64 + n * 16 + lr;
        #pragma unroll
        for (int r = 0; r < 4; ++r)
          C[(row0 + r) * Ndim + col] = (float)acc[s * 2 + m][n][r] * sc[r];
      }
    }
  }
}

// ---- fallback if d_ws is too small: simple tiled fp32 GEMM ----
__global__ void fallback_gemm(const float* __restrict__ x,
                              const float* __restrict__ w,
                              float* __restrict__ C) {
  __shared__ float As[16][17];
  __shared__ float Bs[16][17];
  int tx = threadIdx.x, ty = threadIdx.y;
  long row = (long)blockIdx.y * 16 + ty;
  long col = (long)blockIdx.x * 16 + tx;
  float s = 0.f;
  for (int k0 = 0; k0 < Kdim; k0 += 16) {
    As[ty][tx] = x[row * Kdim + k0 + tx];
    float v = w[(long)(k0 + ty) * Ndim + col];
    Bs[ty][tx] = (fabsf(v) > THRESH) ? (v > 0.f ? 1.f : -1.f) : 0.f;
    __syncthreads();
    #pragma unroll
    for (int k = 0; k < 16; ++k) s += As[ty][k] * Bs[k][tx];
    __syncthreads();
  }
  C[row * Ndim + col] = s;
}

extern "C" void kernel_launch(void* const* d_in, const int* in_sizes, int n_in,
                              void* d_out, int out_size, void* d_ws, size_t ws_size,
                              hipStream_t stream) {
  const float* x = (const float*)d_in[0];
  const float* w = (const float*)d_in[1];
  float* out = (float*)d_out;

  size_t abytes = (size_t)Mdim * Kdim;      // 16 MB i8
  size_t bbytes = (size_t)Ndim * Kdim;      // 16 MB i8
  size_t sbytes = (size_t)Mdim * 4;         // 32 KB scales

  if (ws_size >= abytes + bbytes + sbytes) {
    signed char* xq = (signed char*)d_ws;
    signed char* bt = (signed char*)d_ws + abytes;
    float* scales = (float*)((char*)d_ws + abytes + bbytes);
    xq_kernel<<<Mdim, 256, 0, stream>>>(x, xq, scales);
    tern_tr_kernel<<<dim3(Ndim / 32, Kdim / 32), dim3(32, 8), 0, stream>>>(w, bt);
    gemm8_kernel<<<1024, 512, 0, stream>>>(xq, bt, scales, out);
  } else {
    fallback_gemm<<<dim3(Ndim / 16, Mdim / 16), dim3(16, 16), 0, stream>>>(x, w, out);
  }
}